// Round 3
// baseline (12124.648 us; speedup 1.0000x reference)
//
#include <hip/hip_runtime.h>
#include <stdint.h>

#define NB 1024
#define NT 100
#define NPRED 30
#define NE 512
#define NH 1024
#define NG (3*NH)

typedef unsigned short u16;
typedef unsigned int u32;
typedef u16 u16x4 __attribute__((ext_vector_type(4)));
typedef float f32x4 __attribute__((ext_vector_type(4)));
typedef __bf16 bf16x8 __attribute__((ext_vector_type(8)));

__device__ __forceinline__ u16 f2b(float f){
  u32 u = __float_as_uint(f);
  u = (u + 0x7FFFu + ((u >> 16) & 1u)) >> 16;
  return (u16)u;
}
__device__ __forceinline__ float sig_(float x){ return 1.0f/(1.0f+__expf(-x)); }
__device__ __forceinline__ float tanh_(float x){
  float e = __expf(2.0f*fabsf(x));
  return copysignf(1.0f - 2.0f/(e+1.0f), x);
}

// ---------------- fp32 -> bf16 conversion ----------------
__global__ void cvt_kernel(const float* src, u16* dst, int n4){
  int i = blockIdx.x*256 + threadIdx.x;
  if (i < n4){
    f32x4 v = ((const f32x4*)src)[i];
    u16x4 o;
    o[0]=f2b(v[0]); o[1]=f2b(v[1]); o[2]=f2b(v[2]); o[3]=f2b(v[3]);
    ((u16x4*)dst)[i] = o;
  }
}

// ---------------- bulk input embedding for steps [t0, t0+Ce) ----------------
// out[(tc*NB + b)*NE + e]
__global__ void embN_kernel(const float* __restrict__ obs, const float* __restrict__ We,
                            const float* __restrict__ be, u16* __restrict__ out, int t0){
  int idx = blockIdx.x*256 + threadIdx.x;
  int e = idx & 511, rb = idx >> 9;
  int tc = rb >> 10, b = rb & 1023;
  float x0 = obs[(b*NT + t0 + tc)*2], x1 = obs[(b*NT + t0 + tc)*2 + 1];
  out[idx] = f2b(tanh_(We[e*2]*x0 + We[e*2+1]*x1 + be[e]));
}

// single-step variants (prefix recompute / decoder)
__global__ void emb_kernel(const float* __restrict__ obs, const float* __restrict__ We,
                           const float* __restrict__ be, u16* __restrict__ out, int t){
  int idx = blockIdx.x*256 + threadIdx.x;
  int b = idx >> 9, e = idx & 511;
  float x0 = obs[(b*NT + t)*2], x1 = obs[(b*NT + t)*2 + 1];
  out[idx] = f2b(tanh_(We[e*2]*x0 + We[e*2+1]*x1 + be[e]));
}

__global__ void demb_kernel(const float* __restrict__ last, const float* __restrict__ Wed,
                            const float* __restrict__ bed, u16* __restrict__ out){
  int idx = blockIdx.x*256 + threadIdx.x;
  int b = idx >> 9, e = idx & 511;
  out[idx] = f2b(tanh_(Wed[e*2]*last[b*2] + Wed[e*2+1]*last[b*2+1] + bed[e]));
}

// ---------------- core 128x128 bf16 GEMM tile (m97-lite) ----------------
__device__ __forceinline__ void gload16(const u16* g, const u16* lds){
  __builtin_amdgcn_global_load_lds(
      (const __attribute__((address_space(1))) void*)g,
      (__attribute__((address_space(3))) void*)lds, 16, 0, 0);
}

__device__ __forceinline__ void gemm_tile_body(
    const u16* __restrict__ A, int lda,
    const u16* __restrict__ W, int ldw, int K,
    const float* __restrict__ bias, float* __restrict__ C,
    int bRow, int bCol)
{
  __shared__ __align__(16) u16 As[128][32];
  __shared__ __align__(16) u16 Bs[128][32];

  const int tid = threadIdx.x;
  const int w = tid >> 6, l = tid & 63;
  const int wm = w >> 1, wn = w & 1;            // 2x2 waves -> 64x64 per wave
  const int lrow = l >> 2, lcol = (l & 3) * 8;  // staging: 16B per lane
  const int fr = l & 15, fk = (l >> 4) * 8;     // fragment row + k offset

  f32x4 acc[4][4];
  #pragma unroll
  for (int m=0;m<4;m++)
    #pragma unroll
    for (int n=0;n<4;n++) acc[m][n] = (f32x4)0.0f;

  const u16* Ab = A + (size_t)(bRow + lrow)*lda + lcol;
  const u16* Wb = W + (size_t)(bCol + lrow)*ldw + lcol;

  for (int k0 = 0; k0 < K; k0 += 32){
    #pragma unroll
    for (int c=0;c<2;c++){
      int r0 = w*32 + c*16;   // wave-uniform 16-row slab (1024B)
      gload16(Ab + (size_t)r0*lda + k0, &As[r0][0]);
      gload16(Wb + (size_t)r0*ldw + k0, &Bs[r0][0]);
    }
    __syncthreads();

    bf16x8 af[4], bfr[4];
    #pragma unroll
    for (int m=0;m<4;m++) af[m]  = *(const bf16x8*)&As[wm*64 + m*16 + fr][fk];
    #pragma unroll
    for (int n=0;n<4;n++) bfr[n] = *(const bf16x8*)&Bs[wn*64 + n*16 + fr][fk];

    #pragma unroll
    for (int m=0;m<4;m++)
      #pragma unroll
      for (int n=0;n<4;n++)
        acc[m][n] = __builtin_amdgcn_mfma_f32_16x16x32_bf16(af[m], bfr[n], acc[m][n], 0, 0, 0);

    __syncthreads();
  }

  // epilogue: C/D layout col = lane&15, row = (lane>>4)*4 + reg  [m89/m91 verified]
  const int crow = (l >> 4) * 4, ccol = l & 15;
  #pragma unroll
  for (int n=0;n<4;n++){
    int col = bCol + wn*64 + n*16 + ccol;
    float bv = bias ? bias[col] : 0.0f;
    #pragma unroll
    for (int m=0;m<4;m++){
      int row = bRow + wm*64 + m*16 + crow;
      float* Cp = C + (size_t)row*NG + col;
      #pragma unroll
      for (int r=0;r<4;r++) Cp[(size_t)r*NG] = acc[m][n][r] + bv;
    }
  }
}

// big batched GEMM: grid (NG/128, Mrows/128)
__global__ __launch_bounds__(256)
void gemm_big_kernel(const u16* A, int lda, int K, const u16* W,
                     const float* bias, float* C)
{
  gemm_tile_body(A, lda, W, K, K, bias, C, blockIdx.y*128, blockIdx.x*128);
}

// per-step gh GEMM, split-K over z (K=1024 -> 2x512), M=1024 fixed
__global__ __launch_bounds__(256)
void gemm_splitk_kernel(const u16* A, const u16* W, const float* bias,
                        float* C0, float* C1)
{
  int z = blockIdx.z;
  gemm_tile_body(A + z*512, NH, W + z*512, NH, 512,
                 z ? nullptr : bias, z ? C1 : C0,
                 blockIdx.y*128, blockIdx.x*128);
}

// two independent GEMMs in one launch (decoder / prefix recompute)
__global__ __launch_bounds__(256)
void gemm_dual_kernel(
  const u16* A0, int lda0, int K0, const u16* W0, const float* bias0, float* C0,
  const u16* A1, int lda1, int K1, const u16* W1, const float* bias1, float* C1)
{
  if (blockIdx.z == 0)
    gemm_tile_body(A0, lda0, W0, K0, K0, bias0, C0, blockIdx.y*128, blockIdx.x*128);
  else
    gemm_tile_body(A1, lda1, W1, K1, K1, bias1, C1, blockIdx.y*128, blockIdx.x*128);
}

// ---------------- GRU cell: gh = gh0 (+ gh1), fused split-K reduce ----------------
__global__ void gru_cell_kernel(const float* __restrict__ gx,
                                const float* __restrict__ gh0,
                                const float* __restrict__ gh1,
                                const float* __restrict__ hin, float* __restrict__ hout,
                                u16* __restrict__ houtb, u16* __restrict__ seq)
{
  int idx = blockIdx.x*256 + threadIdx.x;   // over NB*NH/4
  int b = idx >> 8, jq = idx & 255;         // NH/4 = 256
  int base = b*768;                         // 3H/4
  const f32x4* gx4 = (const f32x4*)gx;
  const f32x4* g04 = (const f32x4*)gh0;
  f32x4 xr = gx4[base + jq], xz = gx4[base + 256 + jq], xn = gx4[base + 512 + jq];
  f32x4 hr = g04[base + jq], hz = g04[base + 256 + jq], hn = g04[base + 512 + jq];
  if (gh1){
    const f32x4* g14 = (const f32x4*)gh1;
    hr += g14[base + jq]; hz += g14[base + 256 + jq]; hn += g14[base + 512 + jq];
  }
  f32x4 hv = ((const f32x4*)hin)[idx];
  f32x4 o; u16x4 ob;
  #pragma unroll
  for (int c=0;c<4;c++){
    float r = sig_(xr[c] + hr[c]);
    float z = sig_(xz[c] + hz[c]);
    float n = tanh_(xn[c] + r*hn[c]);
    float h = (1.0f - z)*n + z*hv[c];
    o[c] = h; ob[c] = f2b(h);
  }
  ((f32x4*)hout)[idx] = o;
  ((u16x4*)houtb)[idx] = ob;
  if (seq) ((u16x4*)seq)[idx] = ob;
}

// ---------------- output projection: (B,H) @ Wout^T (2,H) + bout ----------------
__global__ void outproj_kernel(const float* __restrict__ h, const float* __restrict__ Wout,
                               const float* __restrict__ bout, float* __restrict__ last,
                               float* __restrict__ dout, int t)
{
  int b = blockIdx.x, tid = threadIdx.x;
  float s0 = 0.f, s1 = 0.f;
  const float* hb_ = h + (size_t)b*NH;
  for (int j = tid; j < NH; j += 256){
    float hv = hb_[j];
    s0 += hv * Wout[j];
    s1 += hv * Wout[NH + j];
  }
  #pragma unroll
  for (int off = 32; off > 0; off >>= 1){
    s0 += __shfl_down(s0, off);
    s1 += __shfl_down(s1, off);
  }
  __shared__ float red[8];
  int w = tid >> 6;
  if ((tid & 63) == 0){ red[w*2] = s0; red[w*2+1] = s1; }
  __syncthreads();
  if (tid == 0){
    float o0 = red[0]+red[2]+red[4]+red[6] + bout[0];
    float o1 = red[1]+red[3]+red[5]+red[7] + bout[1];
    last[b*2]   = o0;
    last[b*2+1] = o1;
    if (dout){ dout[(size_t)b*(NPRED*2) + t*2]     = o0;
               dout[(size_t)b*(NPRED*2) + t*2 + 1] = o1; }
  }
}

extern "C" void kernel_launch(void* const* d_in, const int* in_sizes, int n_in,
                              void* d_out, int out_size, void* d_ws, size_t ws_size,
                              hipStream_t stream)
{
  (void)in_sizes; (void)n_in; (void)out_size;
  const float* obs  = (const float*)d_in[0];
  const float* We   = (const float*)d_in[1];
  const float* be   = (const float*)d_in[2];
  const float* Wed  = (const float*)d_in[3];
  const float* bed  = (const float*)d_in[4];
  const float* e1Wih = (const float*)d_in[5];
  const float* e1Whh = (const float*)d_in[6];
  const float* e1bih = (const float*)d_in[7];
  const float* e1bhh = (const float*)d_in[8];
  const float* e2Wih = (const float*)d_in[9];
  const float* e2Whh = (const float*)d_in[10];
  const float* e2bih = (const float*)d_in[11];
  const float* e2bhh = (const float*)d_in[12];
  const float* d1Wih = (const float*)d_in[13];
  const float* d1Whh = (const float*)d_in[14];
  const float* d1bih = (const float*)d_in[15];
  const float* d1bhh = (const float*)d_in[16];
  const float* d2Wih = (const float*)d_in[17];
  const float* d2Whh = (const float*)d_in[18];
  const float* d2bih = (const float*)d_in[19];
  const float* d2bhh = (const float*)d_in[20];
  const float* Wout = (const float*)d_in[21];
  const float* bout = (const float*)d_in[22];
  float* out = (float*)d_out;

  // ---- fixed workspace allocations (~84 MB) ----
  char* ws = (char*)d_ws;
  size_t off = 0;
  auto alloc = [&](size_t bytes)->char* {
    char* p = ws + off;
    off += (bytes + 255) & ~(size_t)255;
    return p;
  };
  u16* wE1i = (u16*)alloc((size_t)NG*NE*2);
  u16* wE1h = (u16*)alloc((size_t)NG*NH*2);
  u16* wE2i = (u16*)alloc((size_t)NG*NH*2);
  u16* wE2h = (u16*)alloc((size_t)NG*NH*2);
  u16* wD1i = (u16*)alloc((size_t)NG*NE*2);
  u16* wD1h = (u16*)alloc((size_t)NG*NH*2);
  u16* wD2i = (u16*)alloc((size_t)NG*NH*2);
  u16* wD2h = (u16*)alloc((size_t)NG*NH*2);
  u16* embb  = (u16*)alloc((size_t)NB*NE*2);
  float* h1f = (float*)alloc((size_t)NB*NH*4);
  u16*   h1b = (u16*)alloc((size_t)NB*NH*2);
  float* h2f = (float*)alloc((size_t)NB*NH*4);
  u16*   h2b = (u16*)alloc((size_t)NB*NH*2);
  float* ghA = (float*)alloc((size_t)NB*NG*4);
  float* ghB = (float*)alloc((size_t)NB*NG*4);
  float* last = (float*)alloc((size_t)NB*2*4);

  // ---- ws-adaptive: enc1 cache (priority) + gx chunk buffers ----
  const size_t slot = (size_t)NB*NH*2;                                  // 2 MB/step
  const size_t chunk_unit = (size_t)NB*NE*2 + (size_t)NB*NG*4 + 512;    // ~13.6 MB
  size_t rem = (ws_size > off) ? ws_size - off : 0;
  int cs = 0, C = 1;
  if (rem > chunk_unit + (1u<<20)){
    size_t rem2 = rem - chunk_unit - (1u<<20);
    cs = (int)(rem2 / slot); if (cs > NT) cs = NT;
    rem2 -= (size_t)cs * slot;
    C = 1 + (int)(rem2 / chunk_unit);
    if (C > 25) C = 25; if (C > NT) C = NT;
  }
  u16* cache = (u16*)alloc((size_t)cs * slot);
  u16* embc  = (u16*)alloc((size_t)C*NB*NE*2);
  float* gxbuf = (float*)alloc((size_t)C*NB*NG*4);
  const int cache_start = NT - cs;

  // ---- init ----
  hipMemsetAsync(h1f, 0, (size_t)NB*NH*4, stream);
  hipMemsetAsync(h1b, 0, (size_t)NB*NH*2, stream);

  auto cvt = [&](const float* src, u16* dst, size_t n){
    int n4 = (int)(n >> 2);
    cvt_kernel<<<dim3((n4 + 255)/256), dim3(256), 0, stream>>>(src, dst, n4);
  };
  cvt(e1Wih, wE1i, (size_t)NG*NE);
  cvt(e1Whh, wE1h, (size_t)NG*NH);
  cvt(e2Wih, wE2i, (size_t)NG*NH);
  cvt(e2Whh, wE2h, (size_t)NG*NH);
  cvt(d1Wih, wD1i, (size_t)NG*NE);
  cvt(d1Whh, wD1h, (size_t)NG*NH);
  cvt(d2Wih, wD2i, (size_t)NG*NH);
  cvt(d2Whh, wD2h, (size_t)NG*NH);

  const dim3 blk(256);
  const dim3 splitk_grid(NG/128, NB/128, 2);   // 24 x 8 x 2 = 768 blocks
  const dim3 dual_grid(NG/128, NB/128, 2);
  const dim3 emb_grid((NB*NE)/256);
  const dim3 cell_grid((NB*NH/4)/256);

  // ---- pass 1: GRU1; gx hoisted into chunked bulk GEMMs ----
  for (int t0 = 0; t0 < NT; t0 += C){
    int Ce = (NT - t0 < C) ? NT - t0 : C;
    embN_kernel<<<dim3(Ce*2048), blk, 0, stream>>>(obs, We, be, embc, t0);
    gemm_big_kernel<<<dim3(NG/128, Ce*8), blk, 0, stream>>>(embc, NE, NE, wE1i, e1bih, gxbuf);
    for (int tc = 0; tc < Ce; ++tc){
      int t = t0 + tc;
      gemm_splitk_kernel<<<splitk_grid, blk, 0, stream>>>(h1b, wE1h, e1bhh, ghA, ghB);
      u16* slot_p = (t >= cache_start) ? cache + (size_t)(t - cache_start)*NB*NH : (u16*)nullptr;
      gru_cell_kernel<<<cell_grid, blk, 0, stream>>>(
          gxbuf + (size_t)tc*NB*NG, ghA, ghB, h1f, h1f, h1b, slot_p);
    }
  }

  // GRU2 initial hidden = GRU1 final hidden (the reference quirk)
  hipMemcpyAsync(h2f, h1f, (size_t)NB*NH*4, hipMemcpyDeviceToDevice, stream);
  hipMemcpyAsync(h2b, h1b, (size_t)NB*NH*2, hipMemcpyDeviceToDevice, stream);

  // ---- pass 2: GRU2 ----
  if (cache_start > 0){
    hipMemsetAsync(h1f, 0, (size_t)NB*NH*4, stream);
    hipMemsetAsync(h1b, 0, (size_t)NB*NH*2, stream);
  }
  // prefix: recompute GRU1 (uncached), interleaved with GRU2 (dual GEMMs)
  for (int t = 0; t < cache_start; ++t){
    emb_kernel<<<emb_grid, blk, 0, stream>>>(obs, We, be, embb, t);
    gemm_dual_kernel<<<dual_grid, blk, 0, stream>>>(
        embb, NE, NE, wE1i, e1bih, gxbuf,
        h1b,  NH, NH, wE1h, e1bhh, ghA);
    gru_cell_kernel<<<cell_grid, blk, 0, stream>>>(gxbuf, ghA, (float*)nullptr, h1f, h1f, h1b, (u16*)nullptr);
    gemm_dual_kernel<<<dual_grid, blk, 0, stream>>>(
        h1b, NH, NH, wE2i, e2bih, gxbuf,
        h2b, NH, NH, wE2h, e2bhh, ghA);
    gru_cell_kernel<<<cell_grid, blk, 0, stream>>>(gxbuf, ghA, (float*)nullptr, h2f, h2f, h2b, (u16*)nullptr);
    if (t == NT - 2)
      outproj_kernel<<<dim3(NB), blk, 0, stream>>>(h2f, Wout, bout, last, (float*)nullptr, 0);
  }
  // cached region: bulk gx2 chunks from enc1 cache
  for (int t0 = cache_start; t0 < NT; t0 += C){
    int Ce = (NT - t0 < C) ? NT - t0 : C;
    gemm_big_kernel<<<dim3(NG/128, Ce*8), blk, 0, stream>>>(
        cache + (size_t)(t0 - cache_start)*NB*NH, NH, NH, wE2i, e2bih, gxbuf);
    for (int tc = 0; tc < Ce; ++tc){
      int t = t0 + tc;
      gemm_splitk_kernel<<<splitk_grid, blk, 0, stream>>>(h2b, wE2h, e2bhh, ghA, ghB);
      gru_cell_kernel<<<cell_grid, blk, 0, stream>>>(
          gxbuf + (size_t)tc*NB*NG, ghA, ghB, h2f, h2f, h2b, (u16*)nullptr);
      if (t == NT - 2)
        outproj_kernel<<<dim3(NB), blk, 0, stream>>>(h2f, Wout, bout, last, (float*)nullptr, 0);
    }
  }

  // ---- autoregressive decoder (carry = h2, intermediate = h1) ----
  for (int t = 0; t < NPRED; ++t){
    demb_kernel<<<emb_grid, blk, 0, stream>>>(last, Wed, bed, embb);
    gemm_dual_kernel<<<dual_grid, blk, 0, stream>>>(
        embb, NE, NE, wD1i, d1bih, gxbuf,
        h2b,  NH, NH, wD1h, d1bhh, ghA);
    gru_cell_kernel<<<cell_grid, blk, 0, stream>>>(gxbuf, ghA, (float*)nullptr, h2f, h1f, h1b, (u16*)nullptr);
    gemm_dual_kernel<<<dual_grid, blk, 0, stream>>>(
        h1b, NH, NH, wD2i, d2bih, gxbuf,
        h1b, NH, NH, wD2h, d2bhh, ghA);
    gru_cell_kernel<<<cell_grid, blk, 0, stream>>>(gxbuf, ghA, (float*)nullptr, h1f, h2f, h2b, (u16*)nullptr);
    outproj_kernel<<<dim3(NB), blk, 0, stream>>>(h2f, Wout, bout, last, out, t);
  }
}